// Round 9
// baseline (1228.320 us; speedup 1.0000x reference)
//
#include <hip/hip_runtime.h>
#include <hip/hip_bf16.h>
#include <math.h>

#define VAR_N 4
#define LEVELS 17
#define NCELLS 56
#define PRED_N 12
#define TSTEPS 4096
#define TROWS (TSTEPS + PRED_N)
#define DT 0.1f
#define RPB 8
#define LOG2E 1.44269504088896340736f
#define TB 8

static __device__ __forceinline__ float rl(float x, int lane) {
    return __int_as_float(__builtin_amdgcn_readlane(__float_as_int(x), lane));
}
static __device__ __forceinline__ float rcpf(float x) {
    return __builtin_amdgcn_rcpf(x);
}

// ---------------------------------------------------------------------------
// Kernel 1: preproc encoder (68->68 x5) fused with gprep (unchanged).
// ---------------------------------------------------------------------------
__global__ void pre_g_kernel(const float* __restrict__ x,
                             const float* __restrict__ w1, const float* __restrict__ b1,
                             const float* __restrict__ w2, const float* __restrict__ b2,
                             const float* __restrict__ w3, const float* __restrict__ b3,
                             const float* __restrict__ w4, const float* __restrict__ b4,
                             const float* __restrict__ w5, const float* __restrict__ b5,
                             const float* __restrict__ wx, const float* __restrict__ bvec,
                             float* __restrict__ g) {
    __shared__ float lds[2 * RPB * 68];
    float* bufA = lds;
    float* bufB = lds + RPB * 68;
    const int r0 = blockIdx.x * RPB;
    const int tid = threadIdx.x;

    for (int idx = tid; idx < RPB * 68; idx += 256)
        bufA[idx] = x[(size_t)r0 * 68 + idx];
    __syncthreads();

    const float* Ws[5] = {w1, w2, w3, w4, w5};
    const float* Bs[5] = {b1, b2, b3, b4, b5};
    for (int L = 0; L < 5; ++L) {
        const float* __restrict__ W = Ws[L];
        const bool act = (L < 4);
        if (tid < 68) {
            const int j = tid;
            float acc[RPB];
            float bj = Bs[L][j];
#pragma unroll
            for (int r = 0; r < RPB; ++r) acc[r] = bj;
            for (int k = 0; k + 4 <= 68; k += 4) {
                float w0v = W[(k + 0) * 68 + j];
                float w1v = W[(k + 1) * 68 + j];
                float w2v = W[(k + 2) * 68 + j];
                float w3v = W[(k + 3) * 68 + j];
#pragma unroll
                for (int r = 0; r < RPB; ++r) {
                    const float4 hx = *(const float4*)(bufA + r * 68 + k);
                    acc[r] = fmaf(hx.x, w0v, fmaf(hx.y, w1v,
                              fmaf(hx.z, w2v, fmaf(hx.w, w3v, acc[r]))));
                }
            }
#pragma unroll
            for (int r = 0; r < RPB; ++r)
                bufB[r * 68 + j] = act ? fmaxf(acc[r], 0.f) : acc[r];
        }
        __syncthreads();
        float* t = bufA; bufA = bufB; bufB = t;
    }

    for (int idx = tid; idx < RPB * 4 * NCELLS; idx += 256) {
        int r = idx / 224;
        int rem = idx - r * 224;
        int q = rem / NCELLS;
        int j = rem - q * NCELLS;
        int gr = r0 + r;
        int v = gr >> 10;
        int trow = ((gr & 1023) << 2) + q;
        const float* arow = bufA + r * 68 + q * LEVELS;
        float acc = bvec[v * NCELLS + j];
#pragma unroll
        for (int l = 0; l < LEVELS; ++l)
            acc = fmaf(arow[l], wx[(v * LEVELS + l) * NCELLS + j], acc);
        g[((size_t)(v * NCELLS + j)) * TSTEPS + trow] = acc * LOG2E;
    }
}

// ---------------------------------------------------------------------------
// Kernel 2: sequential LTC scan (proven R6 internals). Raw h -> H, all 4108
// rows per var (observed + pred).
// ---------------------------------------------------------------------------
__global__ void __launch_bounds__(64, 1) scan_kernel(
    const float* __restrict__ g, const float* __restrict__ wh,
    const float* __restrict__ a, const float* __restrict__ tau,
    const float* __restrict__ wx, const float* __restrict__ wout,
    const float* __restrict__ bout, const float* __restrict__ b,
    float* __restrict__ H) {
    typedef float v2 __attribute__((ext_vector_type(2)));
    const int v = blockIdx.x;
    const int lane = threadIdx.x;
    const bool active = lane < NCELLS;
    const int j = active ? lane : (NCELLS - 1);
    __shared__ __align__(16) float hbuf[64];

    v2 whp[28];
#pragma unroll
    for (int q = 0; q < 28; ++q) {
        float w0 = active ? wh[((size_t)v * NCELLS + 2 * q + 0) * NCELLS + lane] * LOG2E : 0.f;
        float w1 = active ? wh[((size_t)v * NCELLS + 2 * q + 1) * NCELLS + lane] * LOG2E : 0.f;
        v2 t; t.x = w0; t.y = w1;
        whp[q] = t;
    }
    const float alpha = active ? DT * a[v * NCELLS + lane] : 0.f;
    const float cden = active ? 1.f + DT / (tau[v * NCELLS + lane] + 0.5f) : 1.f;

    const float4* __restrict__ gv4 = (const float4*)(g + ((size_t)v * NCELLS + j) * TSTEPS);
    float* __restrict__ hp = H + (size_t)v * TROWS * NCELLS + lane;

    auto cell = [&](float h, float gcur) -> float {
        hbuf[lane] = h;   // ds_write; same-wave DS pipe ordering, no barrier
        const float4* h4 = (const float4*)hbuf;
        float4 hv[14];
#pragma unroll
        for (int q = 0; q < 14; ++q) hv[q] = h4[q];   // 14 ds_read_b128, broadcast
        v2 a0 = {0.f, 0.f}, a1 = {0.f, 0.f}, a2 = {0.f, 0.f}, a3 = {0.f, 0.f};
#pragma unroll
        for (int q = 0; q < 7; ++q) {
            float4 hq0 = hv[2 * q];
            float4 hq1 = hv[2 * q + 1];
            v2 p0; p0.x = hq0.x; p0.y = hq0.y;
            v2 p1; p1.x = hq0.z; p1.y = hq0.w;
            v2 p2; p2.x = hq1.x; p2.y = hq1.y;
            v2 p3; p3.x = hq1.z; p3.y = hq1.w;
            a0 = __builtin_elementwise_fma(p0, whp[4 * q + 0], a0);
            a1 = __builtin_elementwise_fma(p1, whp[4 * q + 1], a1);
            a2 = __builtin_elementwise_fma(p2, whp[4 * q + 2], a2);
            a3 = __builtin_elementwise_fma(p3, whp[4 * q + 3], a3);
        }
        v2 s = (a0 + a1) + (a2 + a3);
        float z2 = (gcur + s.x) + s.y;                // log2 domain
        float zc = fmaxf(z2, -80.f);                  // keep e finite
        float e = __builtin_amdgcn_exp2f(-zc);
        float t1 = 1.f + e;
        float num = fmaf(h, t1, alpha);
        float den = fmaf(cden, t1, DT);
        float hn = num * rcpf(den);
        __builtin_amdgcn_sched_group_barrier(0x200, 1, 0);   // DS write
        __builtin_amdgcn_sched_group_barrier(0x100, 14, 0);  // DS reads
        __builtin_amdgcn_sched_group_barrier(0x002, 40, 0);  // VALU
        return hn;
    };

    float h = 0.f;
    float4 gq = gv4[0];
    for (int tq = 0; tq < TSTEPS / 4; ++tq) {
        float4 gn = gq;
        if (tq + 1 < TSTEPS / 4) gn = gv4[tq + 1];   // prefetch ~4 steps ahead
        h = cell(h, gq.x); if (active) hp[0 * NCELLS] = h;
        h = cell(h, gq.y); if (active) hp[1 * NCELLS] = h;
        h = cell(h, gq.z); if (active) hp[2 * NCELLS] = h;
        h = cell(h, gq.w); if (active) hp[3 * NCELLS] = h;
        hp += 4 * NCELLS;
        gq = gn;
    }

    // ---- autoregressive pred phase (12 steps; readlane is fine here) ----
    float wxcol[LEVELS];
#pragma unroll
    for (int l = 0; l < LEVELS; ++l)
        wxcol[l] = active ? wx[(v * LEVELS + l) * NCELLS + lane] * LOG2E : 0.f;
    float wtc[NCELLS];  // lane l (<17) holds wout[:, l]
#pragma unroll
    for (int jj = 0; jj < NCELLS; ++jj)
        wtc[jj] = (lane < LEVELS) ? wout[((size_t)v * NCELLS + jj) * LEVELS + lane] : 0.f;
    const float bj = active ? b[v * NCELLS + lane] * LOG2E : 0.f;
    const float boutl = (lane < LEVELS) ? bout[v * LEVELS + lane] : 0.f;

    float vv = boutl;
#pragma unroll
    for (int jj = 0; jj < NCELLS; ++jj) vv = fmaf(rl(h, jj), wtc[jj], vv);

    for (int i = 0; i < PRED_N; ++i) {
        float z2 = bj;
#pragma unroll
        for (int l = 0; l < LEVELS; ++l) z2 = fmaf(rl(vv, l), wxcol[l], z2);
#pragma unroll
        for (int k = 0; k < NCELLS; ++k) {
            float wk = (k & 1) ? whp[k >> 1].y : whp[k >> 1].x;
            z2 = fmaf(rl(h, k), wk, z2);
        }
        float zc = fmaxf(z2, -80.f);
        float e = __builtin_amdgcn_exp2f(-zc);
        float t1 = 1.f + e;
        h = fmaf(h, t1, alpha) * rcpf(fmaf(cden, t1, DT));
        if (active) hp[0] = h;     // H row TSTEPS+i
        hp += NCELLS;
        vv = boutl;
#pragma unroll
        for (int jj = 0; jj < NCELLS; ++jj) vv = fmaf(rl(h, jj), wtc[jj], vv);
    }
}

// ---------------------------------------------------------------------------
// Kernel 3: proj + c1 + c2 fused. ONE WAVE per block, TB=8 t-values.
// Lane = output column with NP register passes; acc[rows][NP] so each
// activation float4 is LDS-read ONCE per (row,chunk) per block and reused
// across all column passes (weights in registers). No multi-wave re-reads.
// ---------------------------------------------------------------------------
template <int R, int NP>
static __device__ __forceinline__ void layerW(
    const float* __restrict__ in, int si, int r0,
    float* __restrict__ outb, int so,
    const float* __restrict__ W, const float* __restrict__ B,
    int din, int dout, bool dorelu, int lane) {
    float acc[R][NP];
#pragma unroll
    for (int p = 0; p < NP; ++p) {
        int jj = lane + 64 * p;
        float bj = (jj < dout) ? B[jj] : 0.f;
#pragma unroll
        for (int r = 0; r < R; ++r) acc[r][p] = bj;
    }
    int k = 0;
    for (; k + 4 <= din; k += 4) {
        float w[NP][4];
#pragma unroll
        for (int p = 0; p < NP; ++p) {
            int jj = lane + 64 * p;
            if (jj < dout) {
#pragma unroll
                for (int i = 0; i < 4; ++i) w[p][i] = W[(size_t)(k + i) * dout + jj];
            } else {
#pragma unroll
                for (int i = 0; i < 4; ++i) w[p][i] = 0.f;
            }
        }
#pragma unroll
        for (int r = 0; r < R; ++r) {
            const float4 hx = *(const float4*)(in + (r0 + r) * si + k);
#pragma unroll
            for (int p = 0; p < NP; ++p)
                acc[r][p] = fmaf(hx.x, w[p][0], fmaf(hx.y, w[p][1],
                             fmaf(hx.z, w[p][2], fmaf(hx.w, w[p][3], acc[r][p]))));
        }
    }
    for (; k < din; ++k) {
        float w[NP];
#pragma unroll
        for (int p = 0; p < NP; ++p) {
            int jj = lane + 64 * p;
            w[p] = (jj < dout) ? W[(size_t)k * dout + jj] : 0.f;
        }
#pragma unroll
        for (int r = 0; r < R; ++r) {
            float hv = in[(r0 + r) * si + k];
#pragma unroll
            for (int p = 0; p < NP; ++p) acc[r][p] = fmaf(hv, w[p], acc[r][p]);
        }
    }
#pragma unroll
    for (int p = 0; p < NP; ++p) {
        int jj = lane + 64 * p;
        if (jj < dout) {
#pragma unroll
            for (int r = 0; r < R; ++r)
                outb[(r0 + r) * so + jj] = dorelu ? fmaxf(acc[r][p], 0.f) : acc[r][p];
        }
    }
}

// 32 rows x (17 -> 17), strides 20, relu; lane l<17 active
static __device__ __forceinline__ void layerN(
    const float* __restrict__ in, float* __restrict__ outb,
    const float* __restrict__ W, const float* __restrict__ B, int lane) {
    if (lane < 17) {
        const int l = lane;
        float acc[32];
        float bl = B[l];
#pragma unroll
        for (int r = 0; r < 32; ++r) acc[r] = bl;
        for (int k = 0; k + 4 <= 17; k += 4) {
            float w0 = W[(k + 0) * 17 + l], w1 = W[(k + 1) * 17 + l];
            float w2 = W[(k + 2) * 17 + l], w3 = W[(k + 3) * 17 + l];
#pragma unroll
            for (int r = 0; r < 32; ++r) {
                const float4 hx = *(const float4*)(in + r * 20 + k);
                acc[r] = fmaf(hx.x, w0, fmaf(hx.y, w1, fmaf(hx.z, w2, fmaf(hx.w, w3, acc[r]))));
            }
        }
        float w16 = W[16 * 17 + l];
#pragma unroll
        for (int r = 0; r < 32; ++r)
            outb[r * 20 + l] = fmaxf(fmaf(in[r * 20 + 16], w16, acc[r]), 0.f);
    }
}

__global__ void __launch_bounds__(64) c1c2_kernel(
    const float* __restrict__ H,
    const float* __restrict__ wout, const float* __restrict__ bout,
    const float* __restrict__ c1w1, const float* __restrict__ c1b1,
    const float* __restrict__ c1w2, const float* __restrict__ c1b2,
    const float* __restrict__ c1w3, const float* __restrict__ c1b3,
    const float* __restrict__ c1w4, const float* __restrict__ c1b4,
    const float* __restrict__ c1w5, const float* __restrict__ c1b5,
    const float* __restrict__ c2w1, const float* __restrict__ c2b1,
    const float* __restrict__ c2w2, const float* __restrict__ c2b2,
    const float* __restrict__ c2w3, const float* __restrict__ c2b3,
    const float* __restrict__ c2w4, const float* __restrict__ c2b4,
    const float* __restrict__ c2w5, const float* __restrict__ c2b5,
    float* __restrict__ out) {
    __shared__ __align__(16) float sA[32 * 56];    // H rows, rr = tq*4+v
    __shared__ __align__(16) float sV[32 * 20];    // narrow ping
    __shared__ __align__(16) float sW[32 * 20];    // narrow pong
    __shared__ __align__(16) float sY[TB * 272];   // wide ping (= 32 x 68)
    __shared__ __align__(16) float sZ[TB * 272];   // wide pong
    const int t0 = blockIdx.x * TB;
    const int lane = threadIdx.x;

    // stage H rows (coalesced along j)
    for (int idx = lane; idx < 32 * 56; idx += 64) {
        int row = idx / 56, jj = idx - (idx / 56) * 56;
        int tq = row >> 2, v = row & 3;
        int t = t0 + tq;
        sA[idx] = (t < TROWS) ? H[((size_t)v * TROWS + t) * 56 + jj] : 0.f;
    }
    __syncthreads();

    // ---- projection: vs[rr][l] = H_row . wout[v][:,l] + bout[v][l] ----
    if (lane < 17) {
        const int l = lane;
#pragma unroll
        for (int v = 0; v < 4; ++v) {
            float acc[TB];
            float bl = bout[v * 17 + l];
#pragma unroll
            for (int r = 0; r < TB; ++r) acc[r] = bl;
            for (int k = 0; k < 56; k += 4) {
                float w0 = wout[(v * 56 + k + 0) * 17 + l];
                float w1 = wout[(v * 56 + k + 1) * 17 + l];
                float w2 = wout[(v * 56 + k + 2) * 17 + l];
                float w3 = wout[(v * 56 + k + 3) * 17 + l];
#pragma unroll
                for (int r = 0; r < TB; ++r) {
                    const float4 hx = *(const float4*)(sA + (r * 4 + v) * 56 + k);
                    acc[r] = fmaf(hx.x, w0, fmaf(hx.y, w1, fmaf(hx.z, w2, fmaf(hx.w, w3, acc[r]))));
                }
            }
#pragma unroll
            for (int r = 0; r < TB; ++r) sV[(r * 4 + v) * 20 + l] = acc[r];
        }
    }
    __syncthreads();

    // ---- c1: 17->17->17->68->68->68 (all relu incl. outer) ----
    layerN(sV, sW, c1w1, c1b1, lane);  __syncthreads();
    layerN(sW, sV, c1w2, c1b2, lane);  __syncthreads();
    layerW<16, 2>(sV, 20, 0, sY, 68, c1w3, c1b3, 17, 68, true, lane);
    layerW<16, 2>(sV, 20, 16, sY, 68, c1w3, c1b3, 17, 68, true, lane);
    __syncthreads();
    layerW<16, 2>(sY, 68, 0, sZ, 68, c1w4, c1b4, 68, 68, true, lane);
    layerW<16, 2>(sY, 68, 16, sZ, 68, c1w4, c1b4, 68, 68, true, lane);
    __syncthreads();
    layerW<16, 2>(sZ, 68, 0, sY, 68, c1w5, c1b5, 68, 68, true, lane);
    layerW<16, 2>(sZ, 68, 16, sY, 68, c1w5, c1b5, 68, 68, true, lane);
    __syncthreads();
    // sY is now the TB x 272 c2 input ((tq*4+v)*68+c == tq*272 + v*68+c)

    // ---- c2: 272->272->272->68->68->68 (relu on 1-4, none on 5) ----
    layerW<TB, 5>(sY, 272, 0, sZ, 272, c2w1, c2b1, 272, 272, true, lane);
    __syncthreads();
    layerW<TB, 5>(sZ, 272, 0, sY, 272, c2w2, c2b2, 272, 272, true, lane);
    __syncthreads();
    layerW<TB, 2>(sY, 272, 0, sZ, 68, c2w3, c2b3, 272, 68, true, lane);
    __syncthreads();
    layerW<TB, 2>(sZ, 68, 0, sY, 68, c2w4, c2b4, 68, 68, true, lane);
    __syncthreads();
    layerW<TB, 2>(sY, 68, 0, sZ, 68, c2w5, c2b5, 68, 68, false, lane);
    __syncthreads();

    for (int idx = lane; idx < TB * 68; idx += 64) {
        int r = idx / 68, c = idx - (idx / 68) * 68;
        int t = t0 + r;
        if (t < TROWS) out[(size_t)t * 68 + c] = sZ[r * 68 + c];
    }
}

// ---------------------------------------------------------------------------
extern "C" void kernel_launch(void* const* d_in, const int* in_sizes, int n_in,
                              void* d_out, int out_size, void* d_ws, size_t ws_size,
                              hipStream_t stream) {
    const float* x = (const float*)d_in[0];
    const float* pw[5] = {(const float*)d_in[1], (const float*)d_in[3], (const float*)d_in[5],
                          (const float*)d_in[7], (const float*)d_in[9]};
    const float* pb[5] = {(const float*)d_in[2], (const float*)d_in[4], (const float*)d_in[6],
                          (const float*)d_in[8], (const float*)d_in[10]};
    const float* c1w[5] = {(const float*)d_in[11], (const float*)d_in[13], (const float*)d_in[15],
                           (const float*)d_in[17], (const float*)d_in[19]};
    const float* c1b[5] = {(const float*)d_in[12], (const float*)d_in[14], (const float*)d_in[16],
                           (const float*)d_in[18], (const float*)d_in[20]};
    const float* c2w[5] = {(const float*)d_in[21], (const float*)d_in[23], (const float*)d_in[25],
                           (const float*)d_in[27], (const float*)d_in[29]};
    const float* c2b[5] = {(const float*)d_in[22], (const float*)d_in[24], (const float*)d_in[26],
                           (const float*)d_in[28], (const float*)d_in[30]};
    const float* ltc_wx = (const float*)d_in[31];
    const float* ltc_wh = (const float*)d_in[32];
    const float* ltc_b = (const float*)d_in[33];
    const float* ltc_a = (const float*)d_in[34];
    const float* ltc_tau = (const float*)d_in[35];
    const float* ltc_wout = (const float*)d_in[36];
    const float* ltc_bout = (const float*)d_in[37];

    float* ws = (float*)d_ws;
    float* g = ws;                         // 4*56*4096 = 917504 (transposed, LOG2E-scaled)
    float* H = g + 917504;                 // 4*4108*56 = 920192 (raw h, incl. pred rows)
    float* out = (float*)d_out;            // 4108*68

    // 1) preproc encoder + gprep fused
    pre_g_kernel<<<TSTEPS / RPB, 256, 0, stream>>>(
        x, pw[0], pb[0], pw[1], pb[1], pw[2], pb[2], pw[3], pb[3], pw[4], pb[4],
        ltc_wx, ltc_b, g);

    // 2) sequential LTC scan -> raw H
    scan_kernel<<<VAR_N, 64, 0, stream>>>(g, ltc_wh, ltc_a, ltc_tau, ltc_wx,
                                          ltc_wout, ltc_bout, ltc_b, H);

    // 3) proj + c1 + c2 fused, one wave per block
    c1c2_kernel<<<(TROWS + TB - 1) / TB, 64, 0, stream>>>(
        H, ltc_wout, ltc_bout,
        c1w[0], c1b[0], c1w[1], c1b[1], c1w[2], c1b[2], c1w[3], c1b[3], c1w[4], c1b[4],
        c2w[0], c2b[0], c2w[1], c2b[1], c2w[2], c2b[2], c2w[3], c2b[3], c2w[4], c2b[4],
        out);
}

// Round 10
// 1068.156 us; speedup vs baseline: 1.1499x; 1.1499x over previous
//
#include <hip/hip_runtime.h>
#include <hip/hip_bf16.h>
#include <math.h>

#define VAR_N 4
#define LEVELS 17
#define NCELLS 56
#define PRED_N 12
#define TSTEPS 4096
#define TROWS (TSTEPS + PRED_N)
#define DT 0.1f
#define RPB 8
#define LOG2E 1.44269504088896340736f
#define TB 8

static __device__ __forceinline__ float rl(float x, int lane) {
    return __int_as_float(__builtin_amdgcn_readlane(__float_as_int(x), lane));
}
static __device__ __forceinline__ float rcpf(float x) {
    return __builtin_amdgcn_rcpf(x);
}

// ---------------------------------------------------------------------------
// Kernel 1: preproc encoder (68->68 x5) fused with gprep (unchanged, proven).
// ---------------------------------------------------------------------------
__global__ void pre_g_kernel(const float* __restrict__ x,
                             const float* __restrict__ w1, const float* __restrict__ b1,
                             const float* __restrict__ w2, const float* __restrict__ b2,
                             const float* __restrict__ w3, const float* __restrict__ b3,
                             const float* __restrict__ w4, const float* __restrict__ b4,
                             const float* __restrict__ w5, const float* __restrict__ b5,
                             const float* __restrict__ wx, const float* __restrict__ bvec,
                             float* __restrict__ g) {
    __shared__ float lds[2 * RPB * 68];
    float* bufA = lds;
    float* bufB = lds + RPB * 68;
    const int r0 = blockIdx.x * RPB;
    const int tid = threadIdx.x;

    for (int idx = tid; idx < RPB * 68; idx += 256)
        bufA[idx] = x[(size_t)r0 * 68 + idx];
    __syncthreads();

    const float* Ws[5] = {w1, w2, w3, w4, w5};
    const float* Bs[5] = {b1, b2, b3, b4, b5};
    for (int L = 0; L < 5; ++L) {
        const float* __restrict__ W = Ws[L];
        const bool act = (L < 4);
        if (tid < 68) {
            const int j = tid;
            float acc[RPB];
            float bj = Bs[L][j];
#pragma unroll
            for (int r = 0; r < RPB; ++r) acc[r] = bj;
            for (int k = 0; k + 4 <= 68; k += 4) {
                float w0v = W[(k + 0) * 68 + j];
                float w1v = W[(k + 1) * 68 + j];
                float w2v = W[(k + 2) * 68 + j];
                float w3v = W[(k + 3) * 68 + j];
#pragma unroll
                for (int r = 0; r < RPB; ++r) {
                    const float4 hx = *(const float4*)(bufA + r * 68 + k);
                    acc[r] = fmaf(hx.x, w0v, fmaf(hx.y, w1v,
                              fmaf(hx.z, w2v, fmaf(hx.w, w3v, acc[r]))));
                }
            }
#pragma unroll
            for (int r = 0; r < RPB; ++r)
                bufB[r * 68 + j] = act ? fmaxf(acc[r], 0.f) : acc[r];
        }
        __syncthreads();
        float* t = bufA; bufA = bufB; bufB = t;
    }

    for (int idx = tid; idx < RPB * 4 * NCELLS; idx += 256) {
        int r = idx / 224;
        int rem = idx - r * 224;
        int q = rem / NCELLS;
        int j = rem - q * NCELLS;
        int gr = r0 + r;
        int v = gr >> 10;
        int trow = ((gr & 1023) << 2) + q;
        const float* arow = bufA + r * 68 + q * LEVELS;
        float acc = bvec[v * NCELLS + j];
#pragma unroll
        for (int l = 0; l < LEVELS; ++l)
            acc = fmaf(arow[l], wx[(v * LEVELS + l) * NCELLS + j], acc);
        g[((size_t)(v * NCELLS + j)) * TSTEPS + trow] = acc * LOG2E;
    }
}

// ---------------------------------------------------------------------------
// Kernel 2: sequential LTC scan (R6 internals) + whp pinned to ARCH VGPRs
// via empty asm ("v" class constraint). Theory: allocator parked whp in
// AGPRs (VGPR_Count 72 == hv+misc exactly), paying v_accvgpr_read per fma.
// ---------------------------------------------------------------------------
__global__ void __launch_bounds__(64, 1) scan_kernel(
    const float* __restrict__ g, const float* __restrict__ wh,
    const float* __restrict__ a, const float* __restrict__ tau,
    const float* __restrict__ wx, const float* __restrict__ wout,
    const float* __restrict__ bout, const float* __restrict__ b,
    float* __restrict__ H) {
    typedef float v2 __attribute__((ext_vector_type(2)));
    const int v = blockIdx.x;
    const int lane = threadIdx.x;
    const bool active = lane < NCELLS;
    const int j = active ? lane : (NCELLS - 1);
    __shared__ __align__(16) float hbuf[64];

    v2 whp[28];
#pragma unroll
    for (int q = 0; q < 28; ++q) {
        float w0 = active ? wh[((size_t)v * NCELLS + 2 * q + 0) * NCELLS + lane] * LOG2E : 0.f;
        float w1 = active ? wh[((size_t)v * NCELLS + 2 * q + 1) * NCELLS + lane] * LOG2E : 0.f;
        v2 t; t.x = w0; t.y = w1;
        whp[q] = t;
    }
    // Pin whp to arch VGPRs (prevent AGPR parking -> per-use accvgpr_read).
#pragma unroll
    for (int q = 0; q < 28; ++q) asm volatile("" : "+v"(whp[q]));

    const float alpha = active ? DT * a[v * NCELLS + lane] : 0.f;
    const float cden = active ? 1.f + DT / (tau[v * NCELLS + lane] + 0.5f) : 1.f;

    const float4* __restrict__ gv4 = (const float4*)(g + ((size_t)v * NCELLS + j) * TSTEPS);
    float* __restrict__ hp = H + (size_t)v * TROWS * NCELLS + lane;

    auto cell = [&](float h, float gcur) -> float {
        hbuf[lane] = h;   // ds_write; same-wave DS pipe ordering, no barrier
        const float4* h4 = (const float4*)hbuf;
        float4 hv[14];
#pragma unroll
        for (int q = 0; q < 14; ++q) hv[q] = h4[q];   // 14 ds_read_b128, broadcast
        v2 a0 = {0.f, 0.f}, a1 = {0.f, 0.f}, a2 = {0.f, 0.f}, a3 = {0.f, 0.f};
#pragma unroll
        for (int q = 0; q < 7; ++q) {
            float4 hq0 = hv[2 * q];
            float4 hq1 = hv[2 * q + 1];
            v2 p0; p0.x = hq0.x; p0.y = hq0.y;
            v2 p1; p1.x = hq0.z; p1.y = hq0.w;
            v2 p2; p2.x = hq1.x; p2.y = hq1.y;
            v2 p3; p3.x = hq1.z; p3.y = hq1.w;
            a0 = __builtin_elementwise_fma(p0, whp[4 * q + 0], a0);
            a1 = __builtin_elementwise_fma(p1, whp[4 * q + 1], a1);
            a2 = __builtin_elementwise_fma(p2, whp[4 * q + 2], a2);
            a3 = __builtin_elementwise_fma(p3, whp[4 * q + 3], a3);
        }
        v2 s = (a0 + a1) + (a2 + a3);
        float z2 = (gcur + s.x) + s.y;                // log2 domain
        float zc = fmaxf(z2, -80.f);                  // keep e finite
        float e = __builtin_amdgcn_exp2f(-zc);
        float t1 = 1.f + e;
        float num = fmaf(h, t1, alpha);
        float den = fmaf(cden, t1, DT);
        float hn = num * rcpf(den);
        __builtin_amdgcn_sched_group_barrier(0x200, 1, 0);   // DS write
        __builtin_amdgcn_sched_group_barrier(0x100, 14, 0);  // DS reads
        __builtin_amdgcn_sched_group_barrier(0x002, 40, 0);  // VALU
        return hn;
    };

    float h = 0.f;
    float4 gq = gv4[0];
    for (int tq = 0; tq < TSTEPS / 4; ++tq) {
        float4 gn = gq;
        if (tq + 1 < TSTEPS / 4) gn = gv4[tq + 1];   // prefetch ~4 steps ahead
        h = cell(h, gq.x); if (active) hp[0 * NCELLS] = h;
        h = cell(h, gq.y); if (active) hp[1 * NCELLS] = h;
        h = cell(h, gq.z); if (active) hp[2 * NCELLS] = h;
        h = cell(h, gq.w); if (active) hp[3 * NCELLS] = h;
        hp += 4 * NCELLS;
        gq = gn;
    }

    // ---- autoregressive pred phase (12 steps; readlane is fine here) ----
    float wxcol[LEVELS];
#pragma unroll
    for (int l = 0; l < LEVELS; ++l)
        wxcol[l] = active ? wx[(v * LEVELS + l) * NCELLS + lane] * LOG2E : 0.f;
    float wtc[NCELLS];  // lane l (<17) holds wout[:, l]
#pragma unroll
    for (int jj = 0; jj < NCELLS; ++jj)
        wtc[jj] = (lane < LEVELS) ? wout[((size_t)v * NCELLS + jj) * LEVELS + lane] : 0.f;
    const float bj = active ? b[v * NCELLS + lane] * LOG2E : 0.f;
    const float boutl = (lane < LEVELS) ? bout[v * LEVELS + lane] : 0.f;

    float vv = boutl;
#pragma unroll
    for (int jj = 0; jj < NCELLS; ++jj) vv = fmaf(rl(h, jj), wtc[jj], vv);

    for (int i = 0; i < PRED_N; ++i) {
        float z2 = bj;
#pragma unroll
        for (int l = 0; l < LEVELS; ++l) z2 = fmaf(rl(vv, l), wxcol[l], z2);
#pragma unroll
        for (int k = 0; k < NCELLS; ++k) {
            float wk = (k & 1) ? whp[k >> 1].y : whp[k >> 1].x;
            z2 = fmaf(rl(h, k), wk, z2);
        }
        float zc = fmaxf(z2, -80.f);
        float e = __builtin_amdgcn_exp2f(-zc);
        float t1 = 1.f + e;
        h = fmaf(h, t1, alpha) * rcpf(fmaf(cden, t1, DT));
        if (active) hp[0] = h;     // H row TSTEPS+i
        hp += NCELLS;
        vv = boutl;
#pragma unroll
        for (int jj = 0; jj < NCELLS; ++jj) vv = fmaf(rl(h, jj), wtc[jj], vv);
    }
}

// ---------------------------------------------------------------------------
// Kernel 3: proj + c1 + c2, 256 threads, TB=8 — the measured-best (R7 run:
// 262 us incl. pre_g) layer32/layer8 structure with a proj stage on top.
// ---------------------------------------------------------------------------
static __device__ __forceinline__ void layer32(const float* __restrict__ in, int si,
                                               float* __restrict__ outb, int so,
                                               const float* __restrict__ W,
                                               const float* __restrict__ B,
                                               int din, int dout, bool act, int tid) {
    if (tid < dout) {
        const int j = tid;
        float acc[32];
        float bj = B[j];
#pragma unroll
        for (int r = 0; r < 32; ++r) acc[r] = bj;
        int k = 0;
        for (; k + 4 <= din; k += 4) {
            float w0 = W[(k + 0) * dout + j];
            float w1 = W[(k + 1) * dout + j];
            float w2 = W[(k + 2) * dout + j];
            float w3 = W[(k + 3) * dout + j];
#pragma unroll
            for (int r = 0; r < 32; ++r) {
                const float4 hx = *(const float4*)(in + r * si + k);
                acc[r] = fmaf(hx.x, w0, fmaf(hx.y, w1,
                          fmaf(hx.z, w2, fmaf(hx.w, w3, acc[r]))));
            }
        }
        for (; k < din; ++k) {
            float wv = W[k * dout + j];
#pragma unroll
            for (int r = 0; r < 32; ++r) acc[r] = fmaf(in[r * si + k], wv, acc[r]);
        }
#pragma unroll
        for (int r = 0; r < 32; ++r)
            outb[r * so + j] = act ? fmaxf(acc[r], 0.f) : acc[r];
    }
}

static __device__ __forceinline__ void layer8(const float* __restrict__ in,
                                              float* __restrict__ outb,
                                              const float* __restrict__ W,
                                              const float* __restrict__ B,
                                              int din, int dout, bool act, int tid) {
    for (int j = tid; j < dout; j += 256) {
        float acc[TB];
        float bj = B[j];
#pragma unroll
        for (int r = 0; r < TB; ++r) acc[r] = bj;
        int k = 0;
        for (; k + 4 <= din; k += 4) {
            float w0 = W[(size_t)(k + 0) * dout + j];
            float w1 = W[(size_t)(k + 1) * dout + j];
            float w2 = W[(size_t)(k + 2) * dout + j];
            float w3 = W[(size_t)(k + 3) * dout + j];
#pragma unroll
            for (int r = 0; r < TB; ++r) {
                const float4 hx = *(const float4*)(in + r * 272 + k);
                acc[r] = fmaf(hx.x, w0, fmaf(hx.y, w1,
                          fmaf(hx.z, w2, fmaf(hx.w, w3, acc[r]))));
            }
        }
        for (; k < din; ++k) {
            float wv = W[(size_t)k * dout + j];
#pragma unroll
            for (int r = 0; r < TB; ++r) acc[r] = fmaf(in[r * 272 + k], wv, acc[r]);
        }
#pragma unroll
        for (int r = 0; r < TB; ++r)
            outb[r * 272 + j] = act ? fmaxf(acc[r], 0.f) : acc[r];
    }
}

__global__ void __launch_bounds__(256) c1c2_kernel(
    const float* __restrict__ H,
    const float* __restrict__ wout, const float* __restrict__ bout,
    const float* __restrict__ c1w1, const float* __restrict__ c1b1,
    const float* __restrict__ c1w2, const float* __restrict__ c1b2,
    const float* __restrict__ c1w3, const float* __restrict__ c1b3,
    const float* __restrict__ c1w4, const float* __restrict__ c1b4,
    const float* __restrict__ c1w5, const float* __restrict__ c1b5,
    const float* __restrict__ c2w1, const float* __restrict__ c2b1,
    const float* __restrict__ c2w2, const float* __restrict__ c2b2,
    const float* __restrict__ c2w3, const float* __restrict__ c2b3,
    const float* __restrict__ c2w4, const float* __restrict__ c2b4,
    const float* __restrict__ c2w5, const float* __restrict__ c2b5,
    float* __restrict__ out) {
    __shared__ __align__(16) float sH[32 * 56];
    __shared__ __align__(16) float bA[32 * 20];
    __shared__ __align__(16) float bB[32 * 20];
    __shared__ __align__(16) float bY[TB * 272];   // also viewed as 32 x 68
    __shared__ __align__(16) float bZ[TB * 272];
    const int t0 = blockIdx.x * TB;
    const int tid = threadIdx.x;

    // stage H rows: row = tq*4+v (coalesced along j)
    for (int idx = tid; idx < 32 * 56; idx += 256) {
        int row = idx / 56, jj = idx - (idx / 56) * 56;
        int tq = row >> 2, v = row & 3;
        int t = t0 + tq;
        sH[idx] = (t < TROWS) ? H[((size_t)v * TROWS + t) * 56 + jj] : 0.f;
    }
    __syncthreads();

    // proj: bA[row*20+l] = sH_row . wout[v][:,l] + bout[v][l]
    for (int idx = tid; idx < 32 * 17; idx += 256) {
        int row = idx / 17, l = idx - (idx / 17) * 17;
        int v = row & 3;
        const float* hr = sH + row * 56;
        float acc = bout[v * 17 + l];
        for (int k = 0; k < 56; k += 4) {
            const float4 hx = *(const float4*)(hr + k);
            acc = fmaf(hx.x, wout[(v * 56 + k + 0) * 17 + l],
                   fmaf(hx.y, wout[(v * 56 + k + 1) * 17 + l],
                    fmaf(hx.z, wout[(v * 56 + k + 2) * 17 + l],
                     fmaf(hx.w, wout[(v * 56 + k + 3) * 17 + l], acc))));
        }
        bA[row * 20 + l] = acc;
    }
    __syncthreads();

    layer32(bA, 20, bB, 20, c1w1, c1b1, 17, 17, true, tid);  __syncthreads();
    layer32(bB, 20, bA, 20, c1w2, c1b2, 17, 17, true, tid);  __syncthreads();
    layer32(bA, 20, bY, 68, c1w3, c1b3, 17, 68, true, tid);  __syncthreads();
    layer32(bY, 68, bZ, 68, c1w4, c1b4, 68, 68, true, tid);  __syncthreads();
    layer32(bZ, 68, bY, 68, c1w5, c1b5, 68, 68, true, tid);  __syncthreads();
    // bY is now the 8 x 272 c2 input ((tq*4+v)*68 + c == tq*272 + v*68 + c)
    layer8(bY, bZ, c2w1, c2b1, 272, 272, true, tid);  __syncthreads();
    layer8(bZ, bY, c2w2, c2b2, 272, 272, true, tid);  __syncthreads();
    layer8(bY, bZ, c2w3, c2b3, 272, 68, true, tid);   __syncthreads();
    layer8(bZ, bY, c2w4, c2b4, 68, 68, true, tid);    __syncthreads();
    layer8(bY, bZ, c2w5, c2b5, 68, 68, false, tid);   __syncthreads();

    for (int idx = tid; idx < TB * 68; idx += 256) {
        int tq = idx / 68, c = idx - (idx / 68) * 68;
        int t = t0 + tq;
        if (t < TROWS) out[(size_t)t * 68 + c] = bZ[tq * 272 + c];
    }
}

// ---------------------------------------------------------------------------
extern "C" void kernel_launch(void* const* d_in, const int* in_sizes, int n_in,
                              void* d_out, int out_size, void* d_ws, size_t ws_size,
                              hipStream_t stream) {
    const float* x = (const float*)d_in[0];
    const float* pw[5] = {(const float*)d_in[1], (const float*)d_in[3], (const float*)d_in[5],
                          (const float*)d_in[7], (const float*)d_in[9]};
    const float* pb[5] = {(const float*)d_in[2], (const float*)d_in[4], (const float*)d_in[6],
                          (const float*)d_in[8], (const float*)d_in[10]};
    const float* c1w[5] = {(const float*)d_in[11], (const float*)d_in[13], (const float*)d_in[15],
                           (const float*)d_in[17], (const float*)d_in[19]};
    const float* c1b[5] = {(const float*)d_in[12], (const float*)d_in[14], (const float*)d_in[16],
                           (const float*)d_in[18], (const float*)d_in[20]};
    const float* c2w[5] = {(const float*)d_in[21], (const float*)d_in[23], (const float*)d_in[25],
                           (const float*)d_in[27], (const float*)d_in[29]};
    const float* c2b[5] = {(const float*)d_in[22], (const float*)d_in[24], (const float*)d_in[26],
                           (const float*)d_in[28], (const float*)d_in[30]};
    const float* ltc_wx = (const float*)d_in[31];
    const float* ltc_wh = (const float*)d_in[32];
    const float* ltc_b = (const float*)d_in[33];
    const float* ltc_a = (const float*)d_in[34];
    const float* ltc_tau = (const float*)d_in[35];
    const float* ltc_wout = (const float*)d_in[36];
    const float* ltc_bout = (const float*)d_in[37];

    float* ws = (float*)d_ws;
    float* g = ws;                         // 4*56*4096 = 917504 (transposed, LOG2E-scaled)
    float* H = g + 917504;                 // 4*4108*56 = 920192 (raw h, incl. pred rows)
    float* out = (float*)d_out;            // 4108*68

    // 1) preproc encoder + gprep fused
    pre_g_kernel<<<TSTEPS / RPB, 256, 0, stream>>>(
        x, pw[0], pb[0], pw[1], pb[1], pw[2], pb[2], pw[3], pb[3], pw[4], pb[4],
        ltc_wx, ltc_b, g);

    // 2) sequential LTC scan -> raw H
    scan_kernel<<<VAR_N, 64, 0, stream>>>(g, ltc_wh, ltc_a, ltc_tau, ltc_wx,
                                          ltc_wout, ltc_bout, ltc_b, H);

    // 3) proj + c1 + c2 fused (256 threads, proven structure)
    c1c2_kernel<<<(TROWS + TB - 1) / TB, 256, 0, stream>>>(
        H, ltc_wout, ltc_bout,
        c1w[0], c1b[0], c1w[1], c1b[1], c1w[2], c1b[2], c1w[3], c1b[3], c1w[4], c1b[4],
        c2w[0], c2b[0], c2w[1], c2b[1], c2w[2], c2b[2], c2w[3], c2b[3], c2w[4], c2b[4],
        out);
}

// Round 11
// 1043.509 us; speedup vs baseline: 1.1771x; 1.0236x over previous
//
#include <hip/hip_runtime.h>
#include <hip/hip_bf16.h>
#include <math.h>

#define VAR_N 4
#define LEVELS 17
#define NCELLS 56
#define PRED_N 12
#define TSTEPS 4096
#define TROWS (TSTEPS + PRED_N)
#define DT 0.1f
#define RPB 8
#define LOG2E 1.44269504088896340736f
#define TB 8

static __device__ __forceinline__ float rl(float x, int lane) {
    return __int_as_float(__builtin_amdgcn_readlane(__float_as_int(x), lane));
}
static __device__ __forceinline__ float rcpf(float x) {
    return __builtin_amdgcn_rcpf(x);
}

// ---------------------------------------------------------------------------
// Kernel 1: preproc encoder (68->68 x5) fused with gprep (unchanged, proven).
// ---------------------------------------------------------------------------
__global__ void pre_g_kernel(const float* __restrict__ x,
                             const float* __restrict__ w1, const float* __restrict__ b1,
                             const float* __restrict__ w2, const float* __restrict__ b2,
                             const float* __restrict__ w3, const float* __restrict__ b3,
                             const float* __restrict__ w4, const float* __restrict__ b4,
                             const float* __restrict__ w5, const float* __restrict__ b5,
                             const float* __restrict__ wx, const float* __restrict__ bvec,
                             float* __restrict__ g) {
    __shared__ float lds[2 * RPB * 68];
    float* bufA = lds;
    float* bufB = lds + RPB * 68;
    const int r0 = blockIdx.x * RPB;
    const int tid = threadIdx.x;

    for (int idx = tid; idx < RPB * 68; idx += 256)
        bufA[idx] = x[(size_t)r0 * 68 + idx];
    __syncthreads();

    const float* Ws[5] = {w1, w2, w3, w4, w5};
    const float* Bs[5] = {b1, b2, b3, b4, b5};
    for (int L = 0; L < 5; ++L) {
        const float* __restrict__ W = Ws[L];
        const bool act = (L < 4);
        if (tid < 68) {
            const int j = tid;
            float acc[RPB];
            float bj = Bs[L][j];
#pragma unroll
            for (int r = 0; r < RPB; ++r) acc[r] = bj;
            for (int k = 0; k + 4 <= 68; k += 4) {
                float w0v = W[(k + 0) * 68 + j];
                float w1v = W[(k + 1) * 68 + j];
                float w2v = W[(k + 2) * 68 + j];
                float w3v = W[(k + 3) * 68 + j];
#pragma unroll
                for (int r = 0; r < RPB; ++r) {
                    const float4 hx = *(const float4*)(bufA + r * 68 + k);
                    acc[r] = fmaf(hx.x, w0v, fmaf(hx.y, w1v,
                              fmaf(hx.z, w2v, fmaf(hx.w, w3v, acc[r]))));
                }
            }
#pragma unroll
            for (int r = 0; r < RPB; ++r)
                bufB[r * 68 + j] = act ? fmaxf(acc[r], 0.f) : acc[r];
        }
        __syncthreads();
        float* t = bufA; bufA = bufB; bufB = t;
    }

    for (int idx = tid; idx < RPB * 4 * NCELLS; idx += 256) {
        int r = idx / 224;
        int rem = idx - r * 224;
        int q = rem / NCELLS;
        int j = rem - q * NCELLS;
        int gr = r0 + r;
        int v = gr >> 10;
        int trow = ((gr & 1023) << 2) + q;
        const float* arow = bufA + r * 68 + q * LEVELS;
        float acc = bvec[v * NCELLS + j];
#pragma unroll
        for (int l = 0; l < LEVELS; ++l)
            acc = fmaf(arow[l], wx[(v * LEVELS + l) * NCELLS + j], acc);
        g[((size_t)(v * NCELLS + j)) * TSTEPS + trow] = acc * LOG2E;
    }
}

// ---------------------------------------------------------------------------
// Kernel 2: sequential LTC scan — unchanged (near structural floor:
// per step 1 ds_write + 14 ds_read_b128 issue + VALU + latency ~= 467 cyc).
// ---------------------------------------------------------------------------
__global__ void __launch_bounds__(64, 1) scan_kernel(
    const float* __restrict__ g, const float* __restrict__ wh,
    const float* __restrict__ a, const float* __restrict__ tau,
    const float* __restrict__ wx, const float* __restrict__ wout,
    const float* __restrict__ bout, const float* __restrict__ b,
    float* __restrict__ H) {
    typedef float v2 __attribute__((ext_vector_type(2)));
    const int v = blockIdx.x;
    const int lane = threadIdx.x;
    const bool active = lane < NCELLS;
    const int j = active ? lane : (NCELLS - 1);
    __shared__ __align__(16) float hbuf[64];

    v2 whp[28];
#pragma unroll
    for (int q = 0; q < 28; ++q) {
        float w0 = active ? wh[((size_t)v * NCELLS + 2 * q + 0) * NCELLS + lane] * LOG2E : 0.f;
        float w1 = active ? wh[((size_t)v * NCELLS + 2 * q + 1) * NCELLS + lane] * LOG2E : 0.f;
        v2 t; t.x = w0; t.y = w1;
        whp[q] = t;
    }
    const float alpha = active ? DT * a[v * NCELLS + lane] : 0.f;
    const float cden = active ? 1.f + DT / (tau[v * NCELLS + lane] + 0.5f) : 1.f;

    const float4* __restrict__ gv4 = (const float4*)(g + ((size_t)v * NCELLS + j) * TSTEPS);
    float* __restrict__ hp = H + (size_t)v * TROWS * NCELLS + lane;

    auto cell = [&](float h, float gcur) -> float {
        hbuf[lane] = h;   // ds_write; same-wave DS pipe ordering, no barrier
        const float4* h4 = (const float4*)hbuf;
        float4 hv[14];
#pragma unroll
        for (int q = 0; q < 14; ++q) hv[q] = h4[q];   // 14 ds_read_b128, broadcast
        v2 a0 = {0.f, 0.f}, a1 = {0.f, 0.f}, a2 = {0.f, 0.f}, a3 = {0.f, 0.f};
#pragma unroll
        for (int q = 0; q < 7; ++q) {
            float4 hq0 = hv[2 * q];
            float4 hq1 = hv[2 * q + 1];
            v2 p0; p0.x = hq0.x; p0.y = hq0.y;
            v2 p1; p1.x = hq0.z; p1.y = hq0.w;
            v2 p2; p2.x = hq1.x; p2.y = hq1.y;
            v2 p3; p3.x = hq1.z; p3.y = hq1.w;
            a0 = __builtin_elementwise_fma(p0, whp[4 * q + 0], a0);
            a1 = __builtin_elementwise_fma(p1, whp[4 * q + 1], a1);
            a2 = __builtin_elementwise_fma(p2, whp[4 * q + 2], a2);
            a3 = __builtin_elementwise_fma(p3, whp[4 * q + 3], a3);
        }
        v2 s = (a0 + a1) + (a2 + a3);
        float z2 = (gcur + s.x) + s.y;                // log2 domain
        float zc = fmaxf(z2, -80.f);                  // keep e finite
        float e = __builtin_amdgcn_exp2f(-zc);
        float t1 = 1.f + e;
        float num = fmaf(h, t1, alpha);
        float den = fmaf(cden, t1, DT);
        float hn = num * rcpf(den);
        __builtin_amdgcn_sched_group_barrier(0x200, 1, 0);   // DS write
        __builtin_amdgcn_sched_group_barrier(0x100, 14, 0);  // DS reads
        __builtin_amdgcn_sched_group_barrier(0x002, 40, 0);  // VALU
        return hn;
    };

    float h = 0.f;
    float4 gq = gv4[0];
    for (int tq = 0; tq < TSTEPS / 4; ++tq) {
        float4 gn = gq;
        if (tq + 1 < TSTEPS / 4) gn = gv4[tq + 1];   // prefetch ~4 steps ahead
        h = cell(h, gq.x); if (active) hp[0 * NCELLS] = h;
        h = cell(h, gq.y); if (active) hp[1 * NCELLS] = h;
        h = cell(h, gq.z); if (active) hp[2 * NCELLS] = h;
        h = cell(h, gq.w); if (active) hp[3 * NCELLS] = h;
        hp += 4 * NCELLS;
        gq = gn;
    }

    // ---- autoregressive pred phase (12 steps; readlane is fine here) ----
    float wxcol[LEVELS];
#pragma unroll
    for (int l = 0; l < LEVELS; ++l)
        wxcol[l] = active ? wx[(v * LEVELS + l) * NCELLS + lane] * LOG2E : 0.f;
    float wtc[NCELLS];  // lane l (<17) holds wout[:, l]
#pragma unroll
    for (int jj = 0; jj < NCELLS; ++jj)
        wtc[jj] = (lane < LEVELS) ? wout[((size_t)v * NCELLS + jj) * LEVELS + lane] : 0.f;
    const float bj = active ? b[v * NCELLS + lane] * LOG2E : 0.f;
    const float boutl = (lane < LEVELS) ? bout[v * LEVELS + lane] : 0.f;

    float vv = boutl;
#pragma unroll
    for (int jj = 0; jj < NCELLS; ++jj) vv = fmaf(rl(h, jj), wtc[jj], vv);

    for (int i = 0; i < PRED_N; ++i) {
        float z2 = bj;
#pragma unroll
        for (int l = 0; l < LEVELS; ++l) z2 = fmaf(rl(vv, l), wxcol[l], z2);
#pragma unroll
        for (int k = 0; k < NCELLS; ++k) {
            float wk = (k & 1) ? whp[k >> 1].y : whp[k >> 1].x;
            z2 = fmaf(rl(h, k), wk, z2);
        }
        float zc = fmaxf(z2, -80.f);
        float e = __builtin_amdgcn_exp2f(-zc);
        float t1 = 1.f + e;
        h = fmaf(h, t1, alpha) * rcpf(fmaf(cden, t1, DT));
        if (active) hp[0] = h;     // H row TSTEPS+i
        hp += NCELLS;
        vv = boutl;
#pragma unroll
        for (int jj = 0; jj < NCELLS; ++jj) vv = fmaf(rl(h, jj), wtc[jj], vv);
    }
}

// ---------------------------------------------------------------------------
// Kernel 3: proj + c1 + c2, 256 threads, TB=8. NEW thread mappings to halve
// LDS-read issue: wide layers use 2 cols/thread (adjacent cols -> one float2
// weight load); narrow layers use row-group splits so 136 threads are active
// (vs 17-68 before). Same FLOPs, ~half the DS stream per wave.
// ---------------------------------------------------------------------------
__global__ void __launch_bounds__(256) c1c2_kernel(
    const float* __restrict__ H,
    const float* __restrict__ wout, const float* __restrict__ bout,
    const float* __restrict__ c1w1, const float* __restrict__ c1b1,
    const float* __restrict__ c1w2, const float* __restrict__ c1b2,
    const float* __restrict__ c1w3, const float* __restrict__ c1b3,
    const float* __restrict__ c1w4, const float* __restrict__ c1b4,
    const float* __restrict__ c1w5, const float* __restrict__ c1b5,
    const float* __restrict__ c2w1, const float* __restrict__ c2b1,
    const float* __restrict__ c2w2, const float* __restrict__ c2b2,
    const float* __restrict__ c2w3, const float* __restrict__ c2b3,
    const float* __restrict__ c2w4, const float* __restrict__ c2b4,
    const float* __restrict__ c2w5, const float* __restrict__ c2b5,
    float* __restrict__ out) {
    __shared__ __align__(16) float sH[32 * 56];
    __shared__ __align__(16) float nA[32 * 20];
    __shared__ __align__(16) float nB[32 * 20];
    __shared__ __align__(16) float bY[TB * 272];   // also viewed as 32 x 68 / 8 x 68
    __shared__ __align__(16) float bZ[TB * 272];
    const int t0 = blockIdx.x * TB;
    const int tid = threadIdx.x;

    // stage H rows: row rr = tq*4+v (coalesced along j)
    for (int idx = tid; idx < 32 * 56; idx += 256) {
        int row = idx / 56, jj = idx - (idx / 56) * 56;
        int tq = row >> 2, v = row & 3;
        int t = t0 + tq;
        sH[idx] = (t < TROWS) ? H[((size_t)v * TROWS + t) * 56 + jj] : 0.f;
    }
    __syncthreads();

    // ---- proj (56 -> 17): 136 thr = (l, v, th2); rows (th*4+q)*4+v share v ----
    if (tid < 136) {
        int l = tid % 17;
        int rg = tid / 17;           // 0..7
        int v = rg & 3, th = rg >> 2;
        float acc[4];
        float bl = bout[v * 17 + l];
#pragma unroll
        for (int q = 0; q < 4; ++q) acc[q] = bl;
        for (int k = 0; k < 56; k += 4) {
            float w0 = wout[(v * 56 + k + 0) * 17 + l];
            float w1 = wout[(v * 56 + k + 1) * 17 + l];
            float w2 = wout[(v * 56 + k + 2) * 17 + l];
            float w3 = wout[(v * 56 + k + 3) * 17 + l];
#pragma unroll
            for (int q = 0; q < 4; ++q) {
                const float4 hx = *(const float4*)(sH + ((th * 4 + q) * 4 + v) * 56 + k);
                acc[q] = fmaf(hx.x, w0, fmaf(hx.y, w1, fmaf(hx.z, w2, fmaf(hx.w, w3, acc[q]))));
            }
        }
#pragma unroll
        for (int q = 0; q < 4; ++q) nA[((th * 4 + q) * 4 + v) * 20 + l] = acc[q];
    }
    __syncthreads();

    // ---- c1 L1/L2 (17 -> 17, relu): 136 thr = (l, rowgroup of 4) ----
#pragma unroll
    for (int LL = 0; LL < 2; ++LL) {
        const float* W = LL ? c1w2 : c1w1;
        const float* B = LL ? c1b2 : c1b1;
        const float* in = LL ? nB : nA;
        float* ob = LL ? nA : nB;
        if (tid < 136) {
            int l = tid % 17;
            int rg = tid / 17;       // rows rg*4 .. rg*4+3
            float acc[4];
            float bl = B[l];
#pragma unroll
            for (int q = 0; q < 4; ++q) acc[q] = bl;
            for (int k = 0; k + 4 <= 17; k += 4) {
                float w0 = W[(k + 0) * 17 + l], w1 = W[(k + 1) * 17 + l];
                float w2 = W[(k + 2) * 17 + l], w3 = W[(k + 3) * 17 + l];
#pragma unroll
                for (int q = 0; q < 4; ++q) {
                    const float4 hx = *(const float4*)(in + (rg * 4 + q) * 20 + k);
                    acc[q] = fmaf(hx.x, w0, fmaf(hx.y, w1, fmaf(hx.z, w2, fmaf(hx.w, w3, acc[q]))));
                }
            }
            float w16 = W[16 * 17 + l];
#pragma unroll
            for (int q = 0; q < 4; ++q)
                ob[(rg * 4 + q) * 20 + l] = fmaxf(fmaf(in[(rg * 4 + q) * 20 + 16], w16, acc[q]), 0.f);
        }
        __syncthreads();
    }

    // ---- c1 L3 (17 -> 68, relu): 136 thr = (j, rowgroup of 16), acc[16] ----
    if (tid < 136) {
        int j = tid % 68;
        int rg = tid / 68;           // rows rg*16 .. rg*16+15
        float acc[16];
        float bj = c1b3[j];
#pragma unroll
        for (int r = 0; r < 16; ++r) acc[r] = bj;
        for (int k = 0; k + 4 <= 17; k += 4) {
            float w0 = c1w3[(k + 0) * 68 + j], w1 = c1w3[(k + 1) * 68 + j];
            float w2 = c1w3[(k + 2) * 68 + j], w3 = c1w3[(k + 3) * 68 + j];
#pragma unroll
            for (int r = 0; r < 16; ++r) {
                const float4 hx = *(const float4*)(nA + (rg * 16 + r) * 20 + k);
                acc[r] = fmaf(hx.x, w0, fmaf(hx.y, w1, fmaf(hx.z, w2, fmaf(hx.w, w3, acc[r]))));
            }
        }
        float w16 = c1w3[16 * 68 + j];
#pragma unroll
        for (int r = 0; r < 16; ++r)
            bY[(rg * 16 + r) * 68 + j] = fmaxf(fmaf(nA[(rg * 16 + r) * 20 + 16], w16, acc[r]), 0.f);
    }
    __syncthreads();

    // ---- c1 L4/L5 (68 -> 68, relu incl. outer): 136 thr = (j, rg16) ----
#pragma unroll
    for (int LL = 0; LL < 2; ++LL) {
        const float* W = LL ? c1w5 : c1w4;
        const float* B = LL ? c1b5 : c1b4;
        const float* in = LL ? bZ : bY;
        float* ob = LL ? bY : bZ;
        if (tid < 136) {
            int j = tid % 68;
            int rg = tid / 68;
            float acc[16];
            float bj = B[j];
#pragma unroll
            for (int r = 0; r < 16; ++r) acc[r] = bj;
            for (int k = 0; k < 68; k += 4) {
                float w0 = W[(k + 0) * 68 + j], w1 = W[(k + 1) * 68 + j];
                float w2 = W[(k + 2) * 68 + j], w3 = W[(k + 3) * 68 + j];
#pragma unroll
                for (int r = 0; r < 16; ++r) {
                    const float4 hx = *(const float4*)(in + (rg * 16 + r) * 68 + k);
                    acc[r] = fmaf(hx.x, w0, fmaf(hx.y, w1, fmaf(hx.z, w2, fmaf(hx.w, w3, acc[r]))));
                }
            }
#pragma unroll
            for (int r = 0; r < 16; ++r)
                ob[(rg * 16 + r) * 68 + j] = fmaxf(acc[r], 0.f);
        }
        __syncthreads();
    }
    // bY now = TB x 272 c2 input ((tq*4+v)*68+c == tq*272 + v*68+c)

    // ---- c2 L1/L2 (272 -> 272, relu): 136 thr, 2 adjacent cols (float2 W) --
#pragma unroll
    for (int LL = 0; LL < 2; ++LL) {
        const float* W = LL ? c2w2 : c2w1;
        const float* B = LL ? c2b2 : c2b1;
        const float* in = LL ? bZ : bY;
        float* ob = LL ? bY : bZ;
        if (tid < 136) {
            int j = 2 * tid;         // cols j, j+1
            float acc0[TB], acc1[TB];
            float b0 = B[j], b1 = B[j + 1];
#pragma unroll
            for (int r = 0; r < TB; ++r) { acc0[r] = b0; acc1[r] = b1; }
            for (int k = 0; k < 272; k += 4) {
                float2 w0 = *(const float2*)(W + (size_t)(k + 0) * 272 + j);
                float2 w1 = *(const float2*)(W + (size_t)(k + 1) * 272 + j);
                float2 w2 = *(const float2*)(W + (size_t)(k + 2) * 272 + j);
                float2 w3 = *(const float2*)(W + (size_t)(k + 3) * 272 + j);
#pragma unroll
                for (int r = 0; r < TB; ++r) {
                    const float4 hx = *(const float4*)(in + r * 272 + k);
                    acc0[r] = fmaf(hx.x, w0.x, fmaf(hx.y, w1.x, fmaf(hx.z, w2.x, fmaf(hx.w, w3.x, acc0[r]))));
                    acc1[r] = fmaf(hx.x, w0.y, fmaf(hx.y, w1.y, fmaf(hx.z, w2.y, fmaf(hx.w, w3.y, acc1[r]))));
                }
            }
#pragma unroll
            for (int r = 0; r < TB; ++r) {
                ob[r * 272 + j] = fmaxf(acc0[r], 0.f);
                ob[r * 272 + j + 1] = fmaxf(acc1[r], 0.f);
            }
        }
        __syncthreads();
    }

    // ---- c2 L3 (272 -> 68, relu): 136 thr = (j, rowgroup of 4) -> bZ 8x68 --
    if (tid < 136) {
        int j = tid % 68;
        int rg = tid / 68;           // rows rg*4 .. rg*4+3
        float acc[4];
        float bj = c2b3[j];
#pragma unroll
        for (int r = 0; r < 4; ++r) acc[r] = bj;
        for (int k = 0; k < 272; k += 4) {
            float w0 = c2w3[(size_t)(k + 0) * 68 + j], w1 = c2w3[(size_t)(k + 1) * 68 + j];
            float w2 = c2w3[(size_t)(k + 2) * 68 + j], w3 = c2w3[(size_t)(k + 3) * 68 + j];
#pragma unroll
            for (int r = 0; r < 4; ++r) {
                const float4 hx = *(const float4*)(bY + (rg * 4 + r) * 272 + k);
                acc[r] = fmaf(hx.x, w0, fmaf(hx.y, w1, fmaf(hx.z, w2, fmaf(hx.w, w3, acc[r]))));
            }
        }
#pragma unroll
        for (int r = 0; r < 4; ++r)
            bZ[(rg * 4 + r) * 68 + j] = fmaxf(acc[r], 0.f);
    }
    __syncthreads();

    // ---- c2 L4 (68 -> 68, relu) bZ(8x68) -> bY(8x68); L5 (no relu) -> bZ --
#pragma unroll
    for (int LL = 0; LL < 2; ++LL) {
        const float* W = LL ? c2w5 : c2w4;
        const float* B = LL ? c2b5 : c2b4;
        const float* in = LL ? bY : bZ;
        float* ob = LL ? bZ : bY;
        const bool act = (LL == 0);
        if (tid < 136) {
            int j = tid % 68;
            int rg = tid / 68;       // rows rg*4 .. rg*4+3
            float acc[4];
            float bj = B[j];
#pragma unroll
            for (int r = 0; r < 4; ++r) acc[r] = bj;
            for (int k = 0; k < 68; k += 4) {
                float w0 = W[(k + 0) * 68 + j], w1 = W[(k + 1) * 68 + j];
                float w2 = W[(k + 2) * 68 + j], w3 = W[(k + 3) * 68 + j];
#pragma unroll
                for (int r = 0; r < 4; ++r) {
                    const float4 hx = *(const float4*)(in + (rg * 4 + r) * 68 + k);
                    acc[r] = fmaf(hx.x, w0, fmaf(hx.y, w1, fmaf(hx.z, w2, fmaf(hx.w, w3, acc[r]))));
                }
            }
#pragma unroll
            for (int r = 0; r < 4; ++r)
                ob[(rg * 4 + r) * 68 + j] = act ? fmaxf(acc[r], 0.f) : acc[r];
        }
        __syncthreads();
    }

    for (int idx = tid; idx < TB * 68; idx += 256) {
        int r = idx / 68, c = idx - (idx / 68) * 68;
        int t = t0 + r;
        if (t < TROWS) out[(size_t)t * 68 + c] = bZ[r * 68 + c];
    }
}

// ---------------------------------------------------------------------------
extern "C" void kernel_launch(void* const* d_in, const int* in_sizes, int n_in,
                              void* d_out, int out_size, void* d_ws, size_t ws_size,
                              hipStream_t stream) {
    const float* x = (const float*)d_in[0];
    const float* pw[5] = {(const float*)d_in[1], (const float*)d_in[3], (const float*)d_in[5],
                          (const float*)d_in[7], (const float*)d_in[9]};
    const float* pb[5] = {(const float*)d_in[2], (const float*)d_in[4], (const float*)d_in[6],
                          (const float*)d_in[8], (const float*)d_in[10]};
    const float* c1w[5] = {(const float*)d_in[11], (const float*)d_in[13], (const float*)d_in[15],
                           (const float*)d_in[17], (const float*)d_in[19]};
    const float* c1b[5] = {(const float*)d_in[12], (const float*)d_in[14], (const float*)d_in[16],
                           (const float*)d_in[18], (const float*)d_in[20]};
    const float* c2w[5] = {(const float*)d_in[21], (const float*)d_in[23], (const float*)d_in[25],
                           (const float*)d_in[27], (const float*)d_in[29]};
    const float* c2b[5] = {(const float*)d_in[22], (const float*)d_in[24], (const float*)d_in[26],
                           (const float*)d_in[28], (const float*)d_in[30]};
    const float* ltc_wx = (const float*)d_in[31];
    const float* ltc_wh = (const float*)d_in[32];
    const float* ltc_b = (const float*)d_in[33];
    const float* ltc_a = (const float*)d_in[34];
    const float* ltc_tau = (const float*)d_in[35];
    const float* ltc_wout = (const float*)d_in[36];
    const float* ltc_bout = (const float*)d_in[37];

    float* ws = (float*)d_ws;
    float* g = ws;                         // 4*56*4096 = 917504 (transposed, LOG2E-scaled)
    float* H = g + 917504;                 // 4*4108*56 = 920192 (raw h, incl. pred rows)
    float* out = (float*)d_out;            // 4108*68

    // 1) preproc encoder + gprep fused
    pre_g_kernel<<<TSTEPS / RPB, 256, 0, stream>>>(
        x, pw[0], pb[0], pw[1], pb[1], pw[2], pb[2], pw[3], pb[3], pw[4], pb[4],
        ltc_wx, ltc_b, g);

    // 2) sequential LTC scan -> raw H
    scan_kernel<<<VAR_N, 64, 0, stream>>>(g, ltc_wh, ltc_a, ltc_tau, ltc_wx,
                                          ltc_wout, ltc_bout, ltc_b, H);

    // 3) proj + c1 + c2 fused (halved DS-issue mappings)
    c1c2_kernel<<<(TROWS + TB - 1) / TB, 256, 0, stream>>>(
        H, ltc_wout, ltc_bout,
        c1w[0], c1b[0], c1w[1], c1b[1], c1w[2], c1b[2], c1w[3], c1b[3], c1w[4], c1b[4],
        c2w[0], c2b[0], c2w[1], c2b[1], c2w[2], c2b[2], c2w[3], c2b[3], c2w[4], c2b[4],
        out);
}